// Round 1
// baseline (486.802 us; speedup 1.0000x reference)
//
#include <hip/hip_runtime.h>
#include <math.h>

#define B_ 16
#define H_ 16
#define M_ 256
#define N_ 576
#define D_ 1024

constexpr float EPS_ = 1e-8f;
constexpr float FI_ = 0.90909090909090906f;   // RHO/(RHO+EPSILON) = 1/1.1

__device__ __forceinline__ float wave_reduce(float v) {
#pragma unroll
  for (int o = 32; o > 0; o >>= 1) v += __shfl_down(v, o, 64);
  return v;
}

// One wave per row: inv_norm[row] = rsqrt(sum_d x[row,d]^2 + 1e-12), D = 1024
__global__ __launch_bounds__(256) void rownorm_kernel(const float* __restrict__ x,
                                                      float* __restrict__ inv,
                                                      int rows) {
  int wave = (int)((blockIdx.x * blockDim.x + threadIdx.x) >> 6);
  int lane = threadIdx.x & 63;
  if (wave >= rows) return;
  const float* r = x + (size_t)wave * D_;
  float s = 0.f;
#pragma unroll
  for (int it = 0; it < 4; ++it) {
    float4 v = *(const float4*)&r[it * 256 + lane * 4];
    s += v.x * v.x + v.y * v.y + v.z * v.z + v.w * v.w;
  }
  s = wave_reduce(s);
  if (lane == 0) inv[wave] = rsqrtf(s + 1e-12f);
}

// K[b,m,n] = exp(10*(sim-1)), sim = (y[b,m]·x[b,n]) * yinv[b,m] * xinv[b,n]
// 64x64 tile per block, BK=16, fp32.
__global__ __launch_bounds__(256) void gemm_k_kernel(const float* __restrict__ vis,
                                                     const float* __restrict__ txt,
                                                     const float* __restrict__ xinv,
                                                     const float* __restrict__ yinv,
                                                     float* __restrict__ Kw) {
  __shared__ float As[16][68];  // [k][m], pad to 68 -> 272B row stride (16B aligned)
  __shared__ float Bs[16][68];  // [k][n]
  const int b = blockIdx.z;
  const int m0 = blockIdx.y * 64;
  const int n0 = blockIdx.x * 64;
  const float* Y = txt + (size_t)b * M_ * D_;
  const float* X = vis + (size_t)b * N_ * D_;
  const int t = threadIdx.x;
  const int row = t >> 2;          // 0..63
  const int dl = (t & 3) << 2;     // 0,4,8,12
  const int tm = (t >> 4) << 2;    // 0..60
  const int tn = (t & 15) << 2;    // 0..60

  float acc[4][4] = {};
  for (int d0 = 0; d0 < D_; d0 += 16) {
    float4 ay = *(const float4*)&Y[(size_t)(m0 + row) * D_ + d0 + dl];
    float4 ax = *(const float4*)&X[(size_t)(n0 + row) * D_ + d0 + dl];
    As[dl + 0][row] = ay.x; As[dl + 1][row] = ay.y;
    As[dl + 2][row] = ay.z; As[dl + 3][row] = ay.w;
    Bs[dl + 0][row] = ax.x; Bs[dl + 1][row] = ax.y;
    Bs[dl + 2][row] = ax.z; Bs[dl + 3][row] = ax.w;
    __syncthreads();
#pragma unroll
    for (int k = 0; k < 16; ++k) {
      float4 a4 = *(const float4*)&As[k][tm];
      float4 b4 = *(const float4*)&Bs[k][tn];
      float a[4] = {a4.x, a4.y, a4.z, a4.w};
      float bb[4] = {b4.x, b4.y, b4.z, b4.w};
#pragma unroll
      for (int i = 0; i < 4; ++i)
#pragma unroll
        for (int j = 0; j < 4; ++j) acc[i][j] += a[i] * bb[j];
    }
    __syncthreads();
  }

  float ym[4], xn[4];
#pragma unroll
  for (int i = 0; i < 4; ++i) {
    ym[i] = yinv[b * M_ + m0 + tm + i];
    xn[i] = xinv[b * N_ + n0 + tn + i];
  }
#pragma unroll
  for (int i = 0; i < 4; ++i) {
    float4 o;
    o.x = expf(10.f * (acc[i][0] * ym[i] * xn[0] - 1.f));
    o.y = expf(10.f * (acc[i][1] * ym[i] * xn[1] - 1.f));
    o.z = expf(10.f * (acc[i][2] * ym[i] * xn[2] - 1.f));
    o.w = expf(10.f * (acc[i][3] * ym[i] * xn[3] - 1.f));
    *(float4*)&Kw[((size_t)b * M_ + m0 + tm + i) * N_ + n0 + tn] = o;
  }
}

// One block per batch. 576 threads. 5 Sinkhorn iterations, then emit
// v[b,n] and scale[b,m] = mask*u/(u*(K·v)+EPS) so the loss kernel can form
// P = scale * K * v without materializing it.
__global__ __launch_bounds__(576) void sinkhorn_kernel(const float* __restrict__ Kw,
                                                       const float* __restrict__ mask,
                                                       float* __restrict__ vout,
                                                       float* __restrict__ scale) {
  __shared__ float sh_u[M_];
  __shared__ float sh_v[N_];
  __shared__ float sh_red[9];
  const int b = blockIdx.x;
  const int t = threadIdx.x;
  const float* Kb = Kw + (size_t)b * M_ * N_;

  float mval = (t < M_) ? mask[b * M_ + t] : 0.f;
  float w = wave_reduce(mval);
  if ((t & 63) == 0) sh_red[t >> 6] = w;
  sh_v[t] = 1.f;  // blockDim == N_
  __syncthreads();
  float summ = 0.f;
#pragma unroll
  for (int i = 0; i < 9; ++i) summ += sh_red[i];
  const float nu = mval / (summ + EPS_);
  const float mu = 1.f / (float)N_;

  for (int it = 0; it < 5; ++it) {
    if (t < M_) {
      float s = 0.f;
      const float* rowp = Kb + (size_t)t * N_;
      for (int n4 = 0; n4 < N_ / 4; ++n4) {
        float4 kk = *(const float4*)&rowp[n4 * 4];
        float4 vv = *(const float4*)&sh_v[n4 * 4];
        s += kk.x * vv.x + kk.y * vv.y + kk.z * vv.z + kk.w * vv.w;
      }
      sh_u[t] = powf(nu / (s + EPS_), FI_);
    }
    __syncthreads();
    {
      float s = 0.f;
      for (int m = 0; m < M_; ++m) s += Kb[(size_t)m * N_ + t] * sh_u[m];
      sh_v[t] = powf(mu / (s + EPS_), FI_);
    }
    __syncthreads();
  }

  if (t < M_) {
    float s = 0.f;
    const float* rowp = Kb + (size_t)t * N_;
    for (int n4 = 0; n4 < N_ / 4; ++n4) {
      float4 kk = *(const float4*)&rowp[n4 * 4];
      float4 vv = *(const float4*)&sh_v[n4 * 4];
      s += kk.x * vv.x + kk.y * vv.y + kk.z * vv.z + kk.w * vv.w;
    }
    float u = sh_u[t];
    scale[b * M_ + t] = mval * u / (u * s + EPS_);
  }
  vout[b * N_ + t] = sh_v[t];
}

// loss = -(1/(B*H*M)) * sum_{b,h,m,n} scale[b,m]*K[b,m,n]*v[b,n]*log(student+EPS)
__global__ __launch_bounds__(256) void loss_kernel(const float* __restrict__ student,
                                                   const float* __restrict__ Kw,
                                                   const float* __restrict__ v,
                                                   const float* __restrict__ scale,
                                                   float* __restrict__ out) {
  const unsigned TOT = (unsigned)B_ * H_ * M_ * (N_ / 4);  // 9,437,184
  __shared__ float sh[4];
  float acc = 0.f;
  for (unsigned idx = blockIdx.x * blockDim.x + threadIdx.x; idx < TOT;
       idx += gridDim.x * blockDim.x) {
    unsigned n4 = idx % (N_ / 4);
    unsigned rem = idx / (N_ / 4);
    unsigned m = rem & (M_ - 1);
    rem >>= 8;
    unsigned b = rem >> 4;  // h not needed beyond addressing (student uses idx directly)
    float4 s4 = *(const float4*)&student[(size_t)idx * 4];
    float4 k4 = *(const float4*)&Kw[(size_t)(b * M_ + m) * N_ + n4 * 4];
    float4 v4 = *(const float4*)&v[(size_t)b * N_ + n4 * 4];
    float sc = scale[b * M_ + m];
    float tsum = k4.x * v4.x * __logf(s4.x + EPS_) + k4.y * v4.y * __logf(s4.y + EPS_) +
                 k4.z * v4.z * __logf(s4.z + EPS_) + k4.w * v4.w * __logf(s4.w + EPS_);
    acc -= sc * tsum;
  }
  float w = wave_reduce(acc);
  int lane = threadIdx.x & 63, wv = threadIdx.x >> 6;
  if (lane == 0) sh[wv] = w;
  __syncthreads();
  if (threadIdx.x == 0) {
    float tot = sh[0] + sh[1] + sh[2] + sh[3];
    atomicAdd(out, tot * (1.f / ((float)B_ * H_ * M_)));
  }
}

extern "C" void kernel_launch(void* const* d_in, const int* in_sizes, int n_in,
                              void* d_out, int out_size, void* d_ws, size_t ws_size,
                              hipStream_t stream) {
  const float* student = (const float*)d_in[0];  // (B,H,M,N)
  const float* vis = (const float*)d_in[1];      // (B,N,D)
  const float* txt = (const float*)d_in[2];      // (B,M,D)
  const float* mask = (const float*)d_in[3];     // (B,M)
  float* out = (float*)d_out;

  char* ws = (char*)d_ws;
  const size_t K_BYTES = (size_t)B_ * M_ * N_ * 4;  // 9,437,184
  float* Kw = (float*)ws;
  float* xinv = (float*)(ws + K_BYTES);                          // B*N
  float* yinv = (float*)(ws + K_BYTES + 36864);                  // B*M
  float* vv = (float*)(ws + K_BYTES + 36864 + 16384);            // B*N
  float* scale = (float*)(ws + K_BYTES + 36864 + 16384 + 36864); // B*M

  hipMemsetAsync(d_out, 0, sizeof(float), stream);
  rownorm_kernel<<<(B_ * N_) / 4, 256, 0, stream>>>(vis, xinv, B_ * N_);
  rownorm_kernel<<<(B_ * M_) / 4, 256, 0, stream>>>(txt, yinv, B_ * M_);
  gemm_k_kernel<<<dim3(N_ / 64, M_ / 64, B_), 256, 0, stream>>>(vis, txt, xinv, yinv, Kw);
  sinkhorn_kernel<<<B_, N_, 0, stream>>>(Kw, mask, vv, scale);
  loss_kernel<<<4096, 256, 0, stream>>>(student, Kw, vv, scale, out);
}

// Round 2
// 409.327 us; speedup vs baseline: 1.1893x; 1.1893x over previous
//
#include <hip/hip_runtime.h>
#include <math.h>

#define B_ 16
#define H_ 16
#define M_ 256
#define N_ 576
#define D_ 1024

constexpr float EPS_ = 1e-8f;
constexpr float FI_ = 0.90909090909090906f;   // RHO/(RHO+EPSILON) = 1/1.1

__device__ __forceinline__ float wave_reduce(float v) {
#pragma unroll
  for (int o = 32; o > 0; o >>= 1) v += __shfl_down(v, o, 64);
  return v;
}

// One wave per row: inv_norm[row] = rsqrt(sum_d x[row,d]^2 + 1e-12), D = 1024
__global__ __launch_bounds__(256) void rownorm_kernel(const float* __restrict__ x,
                                                      float* __restrict__ inv,
                                                      int rows) {
  int wave = (int)((blockIdx.x * blockDim.x + threadIdx.x) >> 6);
  int lane = threadIdx.x & 63;
  if (wave >= rows) return;
  const float* r = x + (size_t)wave * D_;
  float s = 0.f;
#pragma unroll
  for (int it = 0; it < 4; ++it) {
    float4 v = *(const float4*)&r[it * 256 + lane * 4];
    s += v.x * v.x + v.y * v.y + v.z * v.z + v.w * v.w;
  }
  s = wave_reduce(s);
  if (lane == 0) inv[wave] = rsqrtf(s + 1e-12f);
}

// K[b,m,n] = exp(10*(sim-1)), sim = (y[b,m]·x[b,n]) * yinv[b,m] * xinv[b,n]
// 64x64 tile per block, BK=16, fp32.
__global__ __launch_bounds__(256) void gemm_k_kernel(const float* __restrict__ vis,
                                                     const float* __restrict__ txt,
                                                     const float* __restrict__ xinv,
                                                     const float* __restrict__ yinv,
                                                     float* __restrict__ Kw) {
  __shared__ float As[16][68];  // [k][m]
  __shared__ float Bs[16][68];  // [k][n]
  const int b = blockIdx.z;
  const int m0 = blockIdx.y * 64;
  const int n0 = blockIdx.x * 64;
  const float* Y = txt + (size_t)b * M_ * D_;
  const float* X = vis + (size_t)b * N_ * D_;
  const int t = threadIdx.x;
  const int row = t >> 2;          // 0..63
  const int dl = (t & 3) << 2;     // 0,4,8,12
  const int tm = (t >> 4) << 2;    // 0..60
  const int tn = (t & 15) << 2;    // 0..60

  float acc[4][4] = {};
  for (int d0 = 0; d0 < D_; d0 += 16) {
    float4 ay = *(const float4*)&Y[(size_t)(m0 + row) * D_ + d0 + dl];
    float4 ax = *(const float4*)&X[(size_t)(n0 + row) * D_ + d0 + dl];
    As[dl + 0][row] = ay.x; As[dl + 1][row] = ay.y;
    As[dl + 2][row] = ay.z; As[dl + 3][row] = ay.w;
    Bs[dl + 0][row] = ax.x; Bs[dl + 1][row] = ax.y;
    Bs[dl + 2][row] = ax.z; Bs[dl + 3][row] = ax.w;
    __syncthreads();
#pragma unroll
    for (int k = 0; k < 16; ++k) {
      float4 a4 = *(const float4*)&As[k][tm];
      float4 b4 = *(const float4*)&Bs[k][tn];
      float a[4] = {a4.x, a4.y, a4.z, a4.w};
      float bb[4] = {b4.x, b4.y, b4.z, b4.w};
#pragma unroll
      for (int i = 0; i < 4; ++i)
#pragma unroll
        for (int j = 0; j < 4; ++j) acc[i][j] += a[i] * bb[j];
    }
    __syncthreads();
  }

  float ym[4], xn[4];
#pragma unroll
  for (int i = 0; i < 4; ++i) {
    ym[i] = yinv[b * M_ + m0 + tm + i];
    xn[i] = xinv[b * N_ + n0 + tn + i];
  }
#pragma unroll
  for (int i = 0; i < 4; ++i) {
    float4 o;
    o.x = expf(10.f * (acc[i][0] * ym[i] * xn[0] - 1.f));
    o.y = expf(10.f * (acc[i][1] * ym[i] * xn[1] - 1.f));
    o.z = expf(10.f * (acc[i][2] * ym[i] * xn[2] - 1.f));
    o.w = expf(10.f * (acc[i][3] * ym[i] * xn[3] - 1.f));
    *(float4*)&Kw[((size_t)b * M_ + m0 + tm + i) * N_ + n0 + tn] = o;
  }
}

// ---------- Sinkhorn as a sequence of wide, shallow launches ----------

// setup: nu[b,m] = mask/(sum(mask)+EPS); v[b,n] = 1
__global__ __launch_bounds__(576) void sink_setup(const float* __restrict__ mask,
                                                  float* __restrict__ nu,
                                                  float* __restrict__ v) {
  __shared__ float sh_red[9];
  const int b = blockIdx.x;
  const int t = threadIdx.x;
  float mval = (t < M_) ? mask[b * M_ + t] : 0.f;
  float w = wave_reduce(mval);
  if ((t & 63) == 0) sh_red[t >> 6] = w;
  __syncthreads();
  float summ = 0.f;
#pragma unroll
  for (int i = 0; i < 9; ++i) summ += sh_red[i];
  if (t < M_) nu[b * M_ + t] = mval / (summ + EPS_);
  v[b * N_ + t] = 1.f;
}

// u-step: one wave per K-row. u[b,m] = (nu/(K·v + EPS))^fi
__global__ __launch_bounds__(256) void sink_u(const float* __restrict__ Kw,
                                              const float* __restrict__ v,
                                              const float* __restrict__ nu,
                                              float* __restrict__ u) {
  const int b = blockIdx.y;
  const int row = blockIdx.x * 4 + (threadIdx.x >> 6);
  const int lane = threadIdx.x & 63;
  const float* rowp = Kw + ((size_t)b * M_ + row) * N_;
  const float* vb = v + b * N_;
  float s = 0.f;
#pragma unroll
  for (int k = 0; k < 9; ++k) s += rowp[lane + 64 * k] * vb[lane + 64 * k];
  s = wave_reduce(s);
  if (lane == 0) {
    int idx = b * M_ + row;
    u[idx] = powf(nu[idx] / (s + EPS_), FI_);
  }
}

// v-step: one block per 64 columns. v[b,n] = (mu/(K^T·u + EPS))^fi
__global__ __launch_bounds__(256) void sink_v(const float* __restrict__ Kw,
                                              const float* __restrict__ u,
                                              float* __restrict__ v) {
  __shared__ float part[4][64];
  const int b = blockIdx.y;
  const int n0 = blockIdx.x * 64;
  const int col = n0 + (threadIdx.x & 63);
  const int g = threadIdx.x >> 6;
  const float* Kb = Kw + (size_t)b * M_ * N_;
  const float* ub = u + b * M_;
  float s = 0.f;
#pragma unroll 8
  for (int m = g * 64; m < (g + 1) * 64; ++m) s += Kb[(size_t)m * N_ + col] * ub[m];
  part[g][threadIdx.x & 63] = s;
  __syncthreads();
  if (threadIdx.x < 64) {
    float tot = part[0][threadIdx.x] + part[1][threadIdx.x] +
                part[2][threadIdx.x] + part[3][threadIdx.x];
    v[b * N_ + n0 + threadIdx.x] = powf((1.f / (float)N_) / (tot + EPS_), FI_);
  }
}

// scale-step: one wave per K-row. scale[b,m] = mask*u/(u*(K·v)+EPS)
__global__ __launch_bounds__(256) void sink_scale(const float* __restrict__ Kw,
                                                  const float* __restrict__ v,
                                                  const float* __restrict__ u,
                                                  const float* __restrict__ mask,
                                                  float* __restrict__ scale) {
  const int b = blockIdx.y;
  const int row = blockIdx.x * 4 + (threadIdx.x >> 6);
  const int lane = threadIdx.x & 63;
  const float* rowp = Kw + ((size_t)b * M_ + row) * N_;
  const float* vb = v + b * N_;
  float s = 0.f;
#pragma unroll
  for (int k = 0; k < 9; ++k) s += rowp[lane + 64 * k] * vb[lane + 64 * k];
  s = wave_reduce(s);
  if (lane == 0) {
    int idx = b * M_ + row;
    float uu = u[idx];
    scale[idx] = mask[idx] * uu / (uu * s + EPS_);
  }
}

// loss = -(1/(B*H*M)) * sum_{b,h,m,n} scale[b,m]*K[b,m,n]*v[b,n]*log(student+EPS)
__global__ __launch_bounds__(256) void loss_kernel(const float* __restrict__ student,
                                                   const float* __restrict__ Kw,
                                                   const float* __restrict__ v,
                                                   const float* __restrict__ scale,
                                                   float* __restrict__ out) {
  const unsigned TOT = (unsigned)B_ * H_ * M_ * (N_ / 4);  // 9,437,184
  __shared__ float sh[4];
  float acc = 0.f;
  for (unsigned idx = blockIdx.x * blockDim.x + threadIdx.x; idx < TOT;
       idx += gridDim.x * blockDim.x) {
    unsigned n4 = idx % (N_ / 4);
    unsigned rem = idx / (N_ / 4);
    unsigned m = rem & (M_ - 1);
    rem >>= 8;
    unsigned b = rem >> 4;
    float4 s4 = *(const float4*)&student[(size_t)idx * 4];
    float4 k4 = *(const float4*)&Kw[(size_t)(b * M_ + m) * N_ + n4 * 4];
    float4 v4 = *(const float4*)&v[(size_t)b * N_ + n4 * 4];
    float sc = scale[b * M_ + m];
    float tsum = k4.x * v4.x * __logf(s4.x + EPS_) + k4.y * v4.y * __logf(s4.y + EPS_) +
                 k4.z * v4.z * __logf(s4.z + EPS_) + k4.w * v4.w * __logf(s4.w + EPS_);
    acc -= sc * tsum;
  }
  float w = wave_reduce(acc);
  int lane = threadIdx.x & 63, wv = threadIdx.x >> 6;
  if (lane == 0) sh[wv] = w;
  __syncthreads();
  if (threadIdx.x == 0) {
    float tot = sh[0] + sh[1] + sh[2] + sh[3];
    atomicAdd(out, tot * (1.f / ((float)B_ * H_ * M_)));
  }
}

extern "C" void kernel_launch(void* const* d_in, const int* in_sizes, int n_in,
                              void* d_out, int out_size, void* d_ws, size_t ws_size,
                              hipStream_t stream) {
  const float* student = (const float*)d_in[0];  // (B,H,M,N)
  const float* vis = (const float*)d_in[1];      // (B,N,D)
  const float* txt = (const float*)d_in[2];      // (B,M,D)
  const float* mask = (const float*)d_in[3];     // (B,M)
  float* out = (float*)d_out;

  char* ws = (char*)d_ws;
  const size_t K_BYTES = (size_t)B_ * M_ * N_ * 4;  // 9,437,184
  float* Kw = (float*)ws;
  char* p = ws + K_BYTES;
  float* xinv = (float*)p; p += B_ * N_ * 4;
  float* yinv = (float*)p; p += B_ * M_ * 4;
  float* vv = (float*)p;   p += B_ * N_ * 4;
  float* scale = (float*)p; p += B_ * M_ * 4;
  float* nu = (float*)p;   p += B_ * M_ * 4;
  float* uu = (float*)p;   p += B_ * M_ * 4;

  hipMemsetAsync(d_out, 0, sizeof(float), stream);
  rownorm_kernel<<<(B_ * N_) / 4, 256, 0, stream>>>(vis, xinv, B_ * N_);
  rownorm_kernel<<<(B_ * M_) / 4, 256, 0, stream>>>(txt, yinv, B_ * M_);
  gemm_k_kernel<<<dim3(N_ / 64, M_ / 64, B_), 256, 0, stream>>>(vis, txt, xinv, yinv, Kw);

  sink_setup<<<B_, N_, 0, stream>>>(mask, nu, vv);
  for (int it = 0; it < 5; ++it) {
    sink_u<<<dim3(M_ / 4, B_), 256, 0, stream>>>(Kw, vv, nu, uu);
    sink_v<<<dim3(N_ / 64, B_), 256, 0, stream>>>(Kw, uu, vv);
  }
  sink_scale<<<dim3(M_ / 4, B_), 256, 0, stream>>>(Kw, vv, uu, mask, scale);

  loss_kernel<<<4096, 256, 0, stream>>>(student, Kw, vv, scale, out);
}

// Round 3
// 348.984 us; speedup vs baseline: 1.3949x; 1.1729x over previous
//
#include <hip/hip_runtime.h>
#include <math.h>

#define B_ 16
#define H_ 16
#define M_ 256
#define N_ 576
#define D_ 1024
#define BK 64
#define LDS_STRIDE (BK + 8)

constexpr float EPS_ = 1e-8f;
constexpr float FI_ = 0.90909090909090906f;   // RHO/(RHO+EPSILON) = 1/1.1

typedef __bf16 bf16x8 __attribute__((ext_vector_type(8)));
typedef float f32x4 __attribute__((ext_vector_type(4)));

__device__ __forceinline__ float wave_reduce(float v) {
#pragma unroll
  for (int o = 32; o > 0; o >>= 1) v += __shfl_down(v, o, 64);
  return v;
}

__device__ __forceinline__ unsigned short f2bf(float f) {
  union { float f; unsigned u; } a; a.f = f;
  unsigned r = a.u + 0x7fff + ((a.u >> 16) & 1);   // RNE
  return (unsigned short)(r >> 16);
}

// One wave per row: out[row,:] = bf16( x[row,:] / ||x[row,:]|| ), D=1024
__global__ __launch_bounds__(256) void norm_bf16_kernel(const float* __restrict__ x,
                                                        unsigned short* __restrict__ out,
                                                        int rows) {
  int wave = (int)((blockIdx.x * blockDim.x + threadIdx.x) >> 6);
  int lane = threadIdx.x & 63;
  if (wave >= rows) return;
  const float* r = x + (size_t)wave * D_;
  float4 v[4];
  float s = 0.f;
#pragma unroll
  for (int it = 0; it < 4; ++it) {
    v[it] = *(const float4*)&r[it * 256 + lane * 4];
    s += v[it].x * v[it].x + v[it].y * v[it].y + v[it].z * v[it].z + v[it].w * v[it].w;
  }
  s = wave_reduce(s);
  s = __shfl(s, 0, 64);
  float inv = rsqrtf(s + 1e-12f);
  unsigned short* o = out + (size_t)wave * D_;
#pragma unroll
  for (int it = 0; it < 4; ++it) {
    ushort4 pk;
    pk.x = f2bf(v[it].x * inv);
    pk.y = f2bf(v[it].y * inv);
    pk.z = f2bf(v[it].z * inv);
    pk.w = f2bf(v[it].w * inv);
    *(ushort4*)&o[it * 256 + lane * 4] = pk;
  }
}

// K[b,m,n] = exp(10*(dot(yb[b,m],xb[b,n]) - 1)), bf16 MFMA 16x16x32,
// 64x64 tile/block, 4 waves each computing a 32x32 sub-tile (2x2 frags).
__global__ __launch_bounds__(256) void gemm_k_mfma(const unsigned short* __restrict__ xb,
                                                   const unsigned short* __restrict__ yb,
                                                   float* __restrict__ Kw) {
  __shared__ unsigned short As[64][LDS_STRIDE];  // y rows (m)
  __shared__ unsigned short Bs[64][LDS_STRIDE];  // x rows (n)
  const int b = blockIdx.z;
  const int m0 = blockIdx.y * 64;
  const int n0 = blockIdx.x * 64;
  const unsigned short* Y = yb + (size_t)b * M_ * D_;
  const unsigned short* X = xb + (size_t)b * N_ * D_;
  const int t = threadIdx.x;
  const int lane = t & 63;
  const int w = t >> 6;
  const int wm = (w & 1) * 32;
  const int wn = (w >> 1) * 32;
  const int lr = t >> 3;         // 0..31 staging row
  const int lc = (t & 7) * 8;    // staging col (bf16 units, 16B chunks)
  const int fr = lane & 15;      // fragment row within 16
  const int fk = (lane >> 4) * 8;  // fragment k offset

  f32x4 acc[2][2] = {};
  for (int k0 = 0; k0 < D_; k0 += BK) {
#pragma unroll
    for (int p = 0; p < 2; ++p) {
      *(uint4*)&As[lr + 32 * p][lc] = *(const uint4*)&Y[(size_t)(m0 + lr + 32 * p) * D_ + k0 + lc];
      *(uint4*)&Bs[lr + 32 * p][lc] = *(const uint4*)&X[(size_t)(n0 + lr + 32 * p) * D_ + k0 + lc];
    }
    __syncthreads();
#pragma unroll
    for (int ks = 0; ks < BK; ks += 32) {
      bf16x8 a[2], bfr[2];
#pragma unroll
      for (int i = 0; i < 2; ++i) {
        a[i] = *(const bf16x8*)&As[wm + i * 16 + fr][ks + fk];
        bfr[i] = *(const bf16x8*)&Bs[wn + i * 16 + fr][ks + fk];
      }
#pragma unroll
      for (int i = 0; i < 2; ++i)
#pragma unroll
        for (int j = 0; j < 2; ++j)
          acc[i][j] = __builtin_amdgcn_mfma_f32_16x16x32_bf16(a[i], bfr[j], acc[i][j], 0, 0, 0);
    }
    __syncthreads();
  }

  // C/D layout: m = (lane>>4)*4 + reg, n = lane&15
  const int cm = (lane >> 4) * 4;
  const int cn = lane & 15;
#pragma unroll
  for (int i = 0; i < 2; ++i)
#pragma unroll
    for (int j = 0; j < 2; ++j)
#pragma unroll
      for (int rg = 0; rg < 4; ++rg) {
        int m = m0 + wm + i * 16 + cm + rg;
        int n = n0 + wn + j * 16 + cn;
        Kw[((size_t)b * M_ + m) * N_ + n] = expf(10.f * (acc[i][j][rg] - 1.f));
      }
}

// ---------- Sinkhorn as a sequence of wide, shallow launches ----------

__global__ __launch_bounds__(576) void sink_setup(const float* __restrict__ mask,
                                                  float* __restrict__ nu,
                                                  float* __restrict__ v) {
  __shared__ float sh_red[9];
  const int b = blockIdx.x;
  const int t = threadIdx.x;
  float mval = (t < M_) ? mask[b * M_ + t] : 0.f;
  float w = wave_reduce(mval);
  if ((t & 63) == 0) sh_red[t >> 6] = w;
  __syncthreads();
  float summ = 0.f;
#pragma unroll
  for (int i = 0; i < 9; ++i) summ += sh_red[i];
  if (t < M_) nu[b * M_ + t] = mval / (summ + EPS_);
  v[b * N_ + t] = 1.f;
}

// u-step: one wave per K-row. u[b,m] = (nu/(K·v + EPS))^fi
__global__ __launch_bounds__(256) void sink_u(const float* __restrict__ Kw,
                                              const float* __restrict__ v,
                                              const float* __restrict__ nu,
                                              float* __restrict__ u) {
  const int b = blockIdx.y;
  const int row = blockIdx.x * 4 + (threadIdx.x >> 6);
  const int lane = threadIdx.x & 63;
  const float* rowp = Kw + ((size_t)b * M_ + row) * N_;
  const float* vb = v + b * N_;
  float s = 0.f;
#pragma unroll
  for (int k = 0; k < 9; ++k) s += rowp[lane + 64 * k] * vb[lane + 64 * k];
  s = wave_reduce(s);
  if (lane == 0) {
    int idx = b * M_ + row;
    u[idx] = powf(nu[idx] / (s + EPS_), FI_);
  }
}

// v-step: one block per 64 columns. v[b,n] = (mu/(K^T·u + EPS))^fi
__global__ __launch_bounds__(256) void sink_v(const float* __restrict__ Kw,
                                              const float* __restrict__ u,
                                              float* __restrict__ v) {
  __shared__ float part[4][64];
  const int b = blockIdx.y;
  const int n0 = blockIdx.x * 64;
  const int col = n0 + (threadIdx.x & 63);
  const int g = threadIdx.x >> 6;
  const float* Kb = Kw + (size_t)b * M_ * N_;
  const float* ub = u + b * M_;
  float s = 0.f;
#pragma unroll 8
  for (int m = g * 64; m < (g + 1) * 64; ++m) s += Kb[(size_t)m * N_ + col] * ub[m];
  part[g][threadIdx.x & 63] = s;
  __syncthreads();
  if (threadIdx.x < 64) {
    float tot = part[0][threadIdx.x] + part[1][threadIdx.x] +
                part[2][threadIdx.x] + part[3][threadIdx.x];
    v[b * N_ + n0 + threadIdx.x] = powf((1.f / (float)N_) / (tot + EPS_), FI_);
  }
}

// scale-step: one wave per K-row. scale[b,m] = mask*u/(u*(K·v)+EPS)
__global__ __launch_bounds__(256) void sink_scale(const float* __restrict__ Kw,
                                                  const float* __restrict__ v,
                                                  const float* __restrict__ u,
                                                  const float* __restrict__ mask,
                                                  float* __restrict__ scale) {
  const int b = blockIdx.y;
  const int row = blockIdx.x * 4 + (threadIdx.x >> 6);
  const int lane = threadIdx.x & 63;
  const float* rowp = Kw + ((size_t)b * M_ + row) * N_;
  const float* vb = v + b * N_;
  float s = 0.f;
#pragma unroll
  for (int k = 0; k < 9; ++k) s += rowp[lane + 64 * k] * vb[lane + 64 * k];
  s = wave_reduce(s);
  if (lane == 0) {
    int idx = b * M_ + row;
    float uu = u[idx];
    scale[idx] = mask[idx] * uu / (uu * s + EPS_);
  }
}

// loss = -(1/(B*H*M)) * sum_{b,h,m,n} scale[b,m]*K[b,m,n]*v[b,n]*log(student+EPS)
__global__ __launch_bounds__(256) void loss_kernel(const float* __restrict__ student,
                                                   const float* __restrict__ Kw,
                                                   const float* __restrict__ v,
                                                   const float* __restrict__ scale,
                                                   float* __restrict__ out) {
  const unsigned TOT = (unsigned)B_ * H_ * M_ * (N_ / 4);  // 9,437,184
  __shared__ float sh[4];
  float acc = 0.f;
  for (unsigned idx = blockIdx.x * blockDim.x + threadIdx.x; idx < TOT;
       idx += gridDim.x * blockDim.x) {
    unsigned n4 = idx % (N_ / 4);
    unsigned rem = idx / (N_ / 4);
    unsigned m = rem & (M_ - 1);
    rem >>= 8;
    unsigned b = rem >> 4;
    float4 s4 = *(const float4*)&student[(size_t)idx * 4];
    float4 k4 = *(const float4*)&Kw[(size_t)(b * M_ + m) * N_ + n4 * 4];
    float4 v4 = *(const float4*)&v[(size_t)b * N_ + n4 * 4];
    float sc = scale[b * M_ + m];
    float tsum = k4.x * v4.x * __logf(s4.x + EPS_) + k4.y * v4.y * __logf(s4.y + EPS_) +
                 k4.z * v4.z * __logf(s4.z + EPS_) + k4.w * v4.w * __logf(s4.w + EPS_);
    acc -= sc * tsum;
  }
  float w = wave_reduce(acc);
  int lane = threadIdx.x & 63, wv = threadIdx.x >> 6;
  if (lane == 0) sh[wv] = w;
  __syncthreads();
  if (threadIdx.x == 0) {
    float tot = sh[0] + sh[1] + sh[2] + sh[3];
    atomicAdd(out, tot * (1.f / ((float)B_ * H_ * M_)));
  }
}

extern "C" void kernel_launch(void* const* d_in, const int* in_sizes, int n_in,
                              void* d_out, int out_size, void* d_ws, size_t ws_size,
                              hipStream_t stream) {
  const float* student = (const float*)d_in[0];  // (B,H,M,N)
  const float* vis = (const float*)d_in[1];      // (B,N,D)
  const float* txt = (const float*)d_in[2];      // (B,M,D)
  const float* mask = (const float*)d_in[3];     // (B,M)
  float* out = (float*)d_out;

  char* ws = (char*)d_ws;
  const size_t K_BYTES = (size_t)B_ * M_ * N_ * 4;  // 9,437,184
  float* Kw = (float*)ws;
  char* p = ws + K_BYTES;
  unsigned short* xb = (unsigned short*)p; p += (size_t)B_ * N_ * D_ * 2;  // 18.9 MB
  unsigned short* ybf = (unsigned short*)p; p += (size_t)B_ * M_ * D_ * 2; // 8.4 MB
  float* vv = (float*)p;    p += B_ * N_ * 4;
  float* scale = (float*)p; p += B_ * M_ * 4;
  float* nu = (float*)p;    p += B_ * M_ * 4;
  float* uu = (float*)p;    p += B_ * M_ * 4;

  hipMemsetAsync(d_out, 0, sizeof(float), stream);
  norm_bf16_kernel<<<(B_ * N_) / 4, 256, 0, stream>>>(vis, xb, B_ * N_);
  norm_bf16_kernel<<<(B_ * M_) / 4, 256, 0, stream>>>(txt, ybf, B_ * M_);
  gemm_k_mfma<<<dim3(N_ / 64, M_ / 64, B_), 256, 0, stream>>>(xb, ybf, Kw);

  sink_setup<<<B_, N_, 0, stream>>>(mask, nu, vv);
  for (int it = 0; it < 5; ++it) {
    sink_u<<<dim3(M_ / 4, B_), 256, 0, stream>>>(Kw, vv, nu, uu);
    sink_v<<<dim3(N_ / 64, B_), 256, 0, stream>>>(Kw, uu, vv);
  }
  sink_scale<<<dim3(M_ / 4, B_), 256, 0, stream>>>(Kw, vv, uu, mask, scale);

  loss_kernel<<<4096, 256, 0, stream>>>(student, Kw, vv, scale, out);
}